// Round 12
// baseline (398.506 us; speedup 1.0000x reference)
//
#include <hip/hip_runtime.h>

#define SN 5
#define BB 2048
#define KK 128
#define DD 64
#define H1 256
#define H2 128

// ws float layout:
//   P1:  [0, 65536)        paired scaled w1: mu4 at f4 idx 2*q, std4 at 2*q+1
//   P2:  [65536, 131072)   paired scaled w2 (same layout)
//   W3S/S3S/SB1/SB2/SB3 as below; sink for ablations at [200000, +8192)
#define P2F   65536
#define W3S   131072
#define S3S   131200
#define SB1F  131328
#define SB2F  131584
#define SB3F  131712
#define N_STD 66049
#define SINK  200000

#define LOG2E 1.4426950408889634f

#if defined(__has_builtin)
#if __has_builtin(__builtin_amdgcn_exp2f)
#define EXP2(x) __builtin_amdgcn_exp2f(x)
#else
#define EXP2(x) __expf(0.6931471805599453f * (x))
#endif
#if __has_builtin(__builtin_amdgcn_rcpf)
#define RCP(x) __builtin_amdgcn_rcpf(x)
#else
#define RCP(x) (1.0f / (x))
#endif
#else
#define EXP2(x) __expf(0.6931471805599453f * (x))
#define RCP(x) (1.0f / (x))
#endif

__device__ __forceinline__ void bar_lgkm() {
  asm volatile("s_waitcnt lgkmcnt(0)\n\ts_barrier" ::: "memory");
}
__device__ __forceinline__ void keep4(float4 v) {
  asm volatile("" :: "v"(v.x), "v"(v.y), "v"(v.z), "v"(v.w));
}

__device__ __forceinline__ float sp_(float x) {
  return (x > 20.f) ? x : log1pf(__expf(x));
}
__device__ __forceinline__ float sig_(float x) { return RCP(1.f + __expf(-x)); }
__device__ __forceinline__ float tanh_fast(float x) {
  float e = EXP2(2.8853900817779268f * x);
  return 1.f - 2.f * RCP(e + 1.f);
}
__device__ __forceinline__ float4 exp2m4_(float4 m, float4 s, float4 e) {
  float4 r;
  r.x = EXP2(m.x + s.x * e.x);
  r.y = EXP2(m.y + s.y * e.y);
  r.z = EXP2(m.z + s.z * e.z);
  r.w = EXP2(m.w + s.w * e.w);
  return r;
}
__device__ __forceinline__ float dot4_(float4 a, float4 b) {
  return a.x * b.x + a.y * b.y + a.z * b.z + a.w * b.w;
}

__global__ __launch_bounds__(256) void prep_kl(
    const float* w_mu1, const float* eta_w1, const float* b_mu1, const float* eta_b1,
    const float* w_mu2, const float* eta_w2, const float* b_mu2, const float* eta_b2,
    const float* w_mu3, const float* eta_w3, const float* b_mu3, const float* eta_b3,
    float* ws, float* kl_out)
{
  int f = blockIdx.x * 256 + threadIdx.x;
  float kle = 0.f;
  if (f < N_STD) {
    float m, s;
    if (f < 32768) {
      m = w_mu1[f]; s = 1e-6f + sp_(eta_w1[f]);
      int pi = f >> 2, c = f & 3;
      ws[8 * pi + c]     = m * LOG2E;
      ws[8 * pi + 4 + c] = s * LOG2E;
    } else if (f < 65536) {
      int g = f - 32768;
      m = w_mu2[g]; s = 1e-6f + sp_(eta_w2[g]);
      int pi = g >> 2, c = g & 3;
      ws[P2F + 8 * pi + c]     = m * LOG2E;
      ws[P2F + 8 * pi + 4 + c] = s * LOG2E;
    } else if (f < 65664) {
      int i = f - 65536;
      m = w_mu3[i]; s = 1e-6f + sp_(eta_w3[i]);
      ws[W3S + i] = m * LOG2E;
      ws[S3S + i] = s * LOG2E;
    } else if (f < 65920) {
      int i = f - 65664;
      m = b_mu1[i]; s = 1e-6f + sp_(eta_b1[i]);
      ws[SB1F + i] = s;
    } else if (f < 66048) {
      int i = f - 65920;
      m = b_mu2[i]; s = 1e-6f + sp_(eta_b2[i]);
      ws[SB2F + i] = s;
    } else {
      m = b_mu3[0]; s = 1e-6f + sp_(eta_b3[0]);
      ws[SB3F] = s;
    }
    kle = -logf(s) + 0.5f * (s * s + m * m - 1.0f);
  }
  __shared__ float red[256];
  red[threadIdx.x] = kle;
  __syncthreads();
  for (int w = 128; w > 0; w >>= 1) {
    if (threadIdx.x < w) red[threadIdx.x] += red[threadIdx.x + w];
    __syncthreads();
  }
  if (threadIdx.x == 0) atomicAdd(kl_out, red[0]);
}

// ===================== real kernel (R8 best, unchanged) =====================
__global__ __launch_bounds__(256, 4) void bayes_main(
    const int* __restrict__ stu_id, const int* __restrict__ exer_id,
    const float* __restrict__ kn_r,
    const float* __restrict__ stu_cnt, const float* __restrict__ exer_cnt,
    const float* __restrict__ s_emb, const float* __restrict__ e_emb,
    const float* __restrict__ k_emb,
    const float* __restrict__ e_disc_mean, const float* __restrict__ e_disc_eta,
    const float* __restrict__ w_sm, const float* __restrict__ b_sm,
    const float* __restrict__ w_ss, const float* __restrict__ b_ss,
    const float* __restrict__ w_km, const float* __restrict__ b_km,
    const float* __restrict__ w_ks, const float* __restrict__ b_ks,
    const float* __restrict__ lam1s, const float* __restrict__ lam2s,
    const float* __restrict__ lam1e, const float* __restrict__ lam2e,
    const float* __restrict__ b_mu1, const float* __restrict__ b_mu2,
    const float* __restrict__ b_mu3,
    const float* __restrict__ eps_stat, const float* __restrict__ eps_kdiff,
    const float* __restrict__ eps_disc,
    const float* __restrict__ eps_w1, const float* __restrict__ eps_b1,
    const float* __restrict__ eps_w2, const float* __restrict__ eps_b2,
    const float* __restrict__ eps_w3, const float* __restrict__ eps_b3,
    const float* __restrict__ tabs,
    float* __restrict__ out)
{
  const int b = blockIdx.x;
  const int t = threadIdx.x;
  const int g = t >> 4, l16 = t & 15;

  __shared__ __align__(16) float cmb[4][DD];
  __shared__ float smean[KK], sstd[KK], kmean[KK], kstd[KK];
  __shared__ float discs[8];
  __shared__ __align__(16) float xs[SN][KK];
  __shared__ __align__(16) float h1s[SN][H1];
  __shared__ __align__(16) float h2s[SN][H2];
  __shared__ float bias1[H1];
  __shared__ float bias2[H2];
  __shared__ float w3v[H2];

  const int stu = stu_id[b], ex = exer_id[b];

  if (t < DD) {
    float sv = s_emb[(size_t)stu * DD + t];
    cmb[0][t] = sv * w_sm[t];
    cmb[1][t] = sv * w_ss[t];
  } else if (t < 2 * DD) {
    int d = t - DD;
    float ev = e_emb[(size_t)ex * DD + d];
    cmb[2][d] = ev * w_km[d];
    cmb[3][d] = ev * w_ks[d];
  }
  bias1[t] = b_mu1[t] + tabs[SB1F + t] * eps_b1[(size_t)b * H1 + t];
  if (t < H2) {
    bias2[t] = b_mu2[t] + tabs[SB2F + t] * eps_b2[(size_t)b * H2 + t];
    w3v[t] = EXP2(tabs[W3S + t] + tabs[S3S + t] * eps_w3[(size_t)b * H2 + t]);
  }
  if (t < SN) {
    float de = sp_(e_disc_eta[ex]);
    discs[t] = sig_(e_disc_mean[ex] + de * eps_disc[(size_t)t * BB + b]);
  }
  bar_lgkm();

  if (t < KK) {
    const int k = t;
    const float4* kr4 = (const float4*)(k_emb + (size_t)k * DD);
    const float4* cA = (const float4*)cmb[0];
    const float4* cB = (const float4*)cmb[1];
    float am = 0.f, as = 0.f;
    #pragma unroll
    for (int j = 0; j < DD / 4; ++j) {
      float4 kv = kr4[j];
      am += dot4_(kv, cA[j]);
      as += dot4_(kv, cB[j]);
    }
    float sdata = sp_(lam1s[0]) * __expf(-sp_(lam2s[0]) * stu_cnt[stu]);
    smean[k] = am + b_sm[0];
    sstd[k]  = sdata + sp_(as + b_ss[0]);
  } else {
    const int k = t - KK;
    const float4* kr4 = (const float4*)(k_emb + (size_t)k * DD);
    const float4* cA = (const float4*)cmb[2];
    const float4* cB = (const float4*)cmb[3];
    float am = 0.f, as = 0.f;
    #pragma unroll
    for (int j = 0; j < DD / 4; ++j) {
      float4 kv = kr4[j];
      am += dot4_(kv, cA[j]);
      as += dot4_(kv, cB[j]);
    }
    float edata = sp_(lam1e[0]) * __expf(-sp_(lam2e[0]) * exer_cnt[ex]);
    kmean[k] = am + b_km[0];
    kstd[k]  = edata + sp_(as + b_ks[0]);
  }

  float esv[SN], ekv[SN], knrv = 0.f;
  if (t < KK) {
    knrv = kn_r[(size_t)b * KK + t];
    #pragma unroll
    for (int s = 0; s < SN; ++s) {
      esv[s] = eps_stat [((size_t)s * BB + b) * KK + t];
      ekv[s] = eps_kdiff[((size_t)s * BB + b) * KK + t];
    }
  }

  const int lane1 = g * 32 + l16;
  const float4* ep1 = (const float4*)(eps_w1 + (size_t)b * H1 * KK) + lane1;
  float4 c0 = ep1[0],    c1 = ep1[16],   c2 = ep1[512],  c3 = ep1[528];
  float4 d0 = ep1[1024], d1 = ep1[1040], d2 = ep1[1536], d3 = ep1[1552];

  bar_lgkm();

  if (t < KK) {
    const int k = t;
    float sm = smean[k], ss = sstd[k], km = kmean[k], ks = kstd[k];
    #pragma unroll
    for (int s = 0; s < SN; ++s) {
      float st = sig_(sm + ss * esv[s]);
      float kd = sig_(km + ks * ekv[s]);
      xs[s][k] = discs[s] * (st - kd) * knrv;
    }
  }
  bar_lgkm();

  {
    const float4* tp = (const float4*)tabs + 2 * lane1;
    #pragma unroll
    for (int p = 0; p < 8; ++p) {
      const int B0 = p * 1024;
      const int C = 2 * B0;
      float4 n0, n1, n2, n3;
      if (p < 6) {
        n0 = ep1[B0 + 2048]; n1 = ep1[B0 + 2064];
        n2 = ep1[B0 + 2560]; n3 = ep1[B0 + 2576];
      }
      float4 m0 = tp[C],        s0 = tp[C + 1];
      float4 m1 = tp[C + 32],   s1 = tp[C + 33];
      float4 m2 = tp[C + 1024], s2v = tp[C + 1025];
      float4 m3 = tp[C + 1056], s3 = tp[C + 1057];
      float4 wA0 = exp2m4_(m0, s0, c0);
      float4 wA1 = exp2m4_(m1, s1, c1);
      float4 wB0 = exp2m4_(m2, s2v, c2);
      float4 wB1 = exp2m4_(m3, s3, c3);

      float red[SN];
      #pragma unroll
      for (int s2 = 0; s2 < SN; ++s2) {
        float4 xa = *(const float4*)&xs[s2][l16 * 4];
        float4 xb = *(const float4*)&xs[s2][64 + l16 * 4];
        float a0 = dot4_(wA0, xa) + dot4_(wA1, xb);
        float a1 = dot4_(wB0, xa) + dot4_(wB1, xb);
        float u0 = __shfl_xor(a0, 8);
        float u1 = __shfl_xor(a1, 8);
        float a = (l16 < 8) ? (a0 + u0) : (a1 + u1);
        a += __shfl_xor(a, 4);
        a += __shfl_xor(a, 2);
        a += __shfl_xor(a, 1);
        red[s2] = a;
      }
      const int o0 = p * 32 + g, o1 = o0 + 16;
      if (l16 == 0) {
        #pragma unroll
        for (int s2 = 0; s2 < SN; ++s2) h1s[s2][o0] = tanh_fast(red[s2] + bias1[o0]);
      } else if (l16 == 8) {
        #pragma unroll
        for (int s2 = 0; s2 < SN; ++s2) h1s[s2][o1] = tanh_fast(red[s2] + bias1[o1]);
      }
      c0 = d0; c1 = d1; c2 = d2; c3 = d3;
      d0 = n0; d1 = n1; d2 = n2; d3 = n3;
    }
  }

  const int lane2 = g * 64 + l16;
  const float4* ep2 = (const float4*)(eps_w2 + (size_t)b * H2 * H1) + lane2;
  float4 fA[8];
  #pragma unroll
  for (int c = 0; c < 4; ++c) {
    fA[c]     = ep2[c * 16];
    fA[4 + c] = ep2[1024 + c * 16];
  }

  bar_lgkm();

  {
    const float4* tp = (const float4*)(tabs + P2F) + 2 * lane2;
    float4 fB[8];
    #pragma unroll
    for (int p = 0; p < 4; ++p) {
      const int B0 = p * 2048;
      const int C = 2 * B0;
      float4 cf[8];
      #pragma unroll
      for (int c = 0; c < 8; ++c) cf[c] = (p & 1) ? fB[c] : fA[c];
      if (p < 3) {
        #pragma unroll
        for (int c = 0; c < 4; ++c) {
          if (p & 1) {
            fA[c]     = ep2[B0 + 2048 + c * 16];
            fA[4 + c] = ep2[B0 + 3072 + c * 16];
          } else {
            fB[c]     = ep2[B0 + 2048 + c * 16];
            fB[4 + c] = ep2[B0 + 3072 + c * 16];
          }
        }
      }
      float a0[SN] = {0.f, 0.f, 0.f, 0.f, 0.f};
      float a1[SN] = {0.f, 0.f, 0.f, 0.f, 0.f};
      #pragma unroll
      for (int c = 0; c < 4; ++c) {
        float4 m0 = tp[C + c * 32],        s0 = tp[C + c * 32 + 1];
        float4 m1 = tp[C + 2048 + c * 32], s1 = tp[C + 2048 + c * 32 + 1];
        float4 w0 = exp2m4_(m0, s0, cf[c]);
        float4 w1 = exp2m4_(m1, s1, cf[4 + c]);
        #pragma unroll
        for (int s2 = 0; s2 < SN; ++s2) {
          float4 h = *(const float4*)&h1s[s2][c * 64 + l16 * 4];
          a0[s2] += dot4_(w0, h);
          a1[s2] += dot4_(w1, h);
        }
      }
      float red[SN];
      #pragma unroll
      for (int s2 = 0; s2 < SN; ++s2) {
        float u0 = __shfl_xor(a0[s2], 8);
        float u1 = __shfl_xor(a1[s2], 8);
        float a = (l16 < 8) ? (a0[s2] + u0) : (a1[s2] + u1);
        a += __shfl_xor(a, 4);
        a += __shfl_xor(a, 2);
        a += __shfl_xor(a, 1);
        red[s2] = a;
      }
      const int o0 = p * 32 + g, o1 = o0 + 16;
      if (l16 == 0) {
        #pragma unroll
        for (int s2 = 0; s2 < SN; ++s2) h2s[s2][o0] = tanh_fast(red[s2] + bias2[o0]);
      } else if (l16 == 8) {
        #pragma unroll
        for (int s2 = 0; s2 < SN; ++s2) h2s[s2][o1] = tanh_fast(red[s2] + bias2[o1]);
      }
    }
  }
  bar_lgkm();

  if (t < 64) {
    float w3a = w3v[t];
    float w3b = w3v[t + 64];
    float part[SN];
    #pragma unroll
    for (int s2 = 0; s2 < SN; ++s2) part[s2] = w3a * h2s[s2][t] + w3b * h2s[s2][t + 64];
    #pragma unroll
    for (int off = 32; off >= 1; off >>= 1) {
      #pragma unroll
      for (int s2 = 0; s2 < SN; ++s2) part[s2] += __shfl_xor(part[s2], off);
    }
    if (t == 0) {
      float bb3 = b_mu3[0] + tabs[SB3F] * eps_b3[b];
      #pragma unroll
      for (int s2 = 0; s2 < SN; ++s2) out[(size_t)s2 * BB + b] = sig_(part[s2] + bb3);
    }
  }
}

// ===================== ablation: memory stream only =====================
__global__ __launch_bounds__(256, 4) void ab_mem(
    const float* __restrict__ eps_w1, const float* __restrict__ eps_w2,
    const float* __restrict__ tabs, float* __restrict__ sink)
{
  const int b = blockIdx.x, t = threadIdx.x;
  const int g = t >> 4, l16 = t & 15;
  const int lane1 = g * 32 + l16;
  const int lane2 = g * 64 + l16;
  const float4* ep1 = (const float4*)(eps_w1 + (size_t)b * H1 * KK) + lane1;
  const float4* tp1 = (const float4*)tabs + 2 * lane1;
  const float4* ep2 = (const float4*)(eps_w2 + (size_t)b * H2 * H1) + lane2;
  const float4* tp2 = (const float4*)(tabs + P2F) + 2 * lane2;

  float4 acc = {0.f, 0.f, 0.f, 0.f};
  // layer-1 stream: 8 passes x (4 eps f4 + 8 tab f4)
  #pragma unroll
  for (int p = 0; p < 8; ++p) {
    const int B0 = p * 1024, C = 2 * B0;
    float4 a = ep1[B0], b2 = ep1[B0 + 16], c = ep1[B0 + 512], d = ep1[B0 + 528];
    float4 e = tp1[C], f = tp1[C + 1], h = tp1[C + 32], i = tp1[C + 33];
    float4 j = tp1[C + 1024], k = tp1[C + 1025], l = tp1[C + 1056], m = tp1[C + 1057];
    acc += a + b2 + c + d + e + f + h + i + j + k + l + m;
  }
  // layer-2 stream: 4 passes x (8 eps f4 + 16 tab f4)
  #pragma unroll
  for (int p = 0; p < 4; ++p) {
    const int B0 = p * 2048, C = 2 * B0;
    #pragma unroll
    for (int c = 0; c < 4; ++c) {
      float4 a = ep2[B0 + c * 16], b2 = ep2[B0 + 1024 + c * 16];
      float4 e = tp2[C + c * 32], f = tp2[C + c * 32 + 1];
      float4 h = tp2[C + 2048 + c * 32], i = tp2[C + 2048 + c * 32 + 1];
      acc += a + b2 + e + f + h + i;
    }
  }
  keep4(acc);
  if (t == 0) sink[b] = acc.x + acc.y + acc.z + acc.w;
}

// ===================== ablation: compute/LDS/barrier skeleton only =====================
__global__ __launch_bounds__(256, 4) void ab_val(
    const float* __restrict__ eps_w1, float* __restrict__ sink)
{
  const int b = blockIdx.x, t = threadIdx.x;
  const int g = t >> 4, l16 = t & 15;
  __shared__ __align__(16) float xs[SN][KK];
  __shared__ __align__(16) float h1s[SN][H1];
  __shared__ __align__(16) float h2s[SN][H2];
  __shared__ float bias1[H1];
  __shared__ float bias2[H2];
  __shared__ float w3v[H2];

  // one real load to seed non-foldable values
  float4 base = ((const float4*)eps_w1)[(((size_t)b << 8) + t) & 8191];
  float4 bn = base;
  bn.x = bn.x * 0.05f - 2.f; bn.y = bn.y * 0.05f - 2.f;
  bn.z = bn.z * 0.05f - 2.f; bn.w = bn.w * 0.05f - 2.f;

  if (t < KK) {
    #pragma unroll
    for (int s = 0; s < SN; ++s) xs[s][t] = bn.x * 0.1f + 0.01f * s;
  }
  bias1[t] = bn.y * 0.01f;
  if (t < H2) { bias2[t] = bn.z * 0.01f; w3v[t] = bn.w * 0.01f + 1.f; }
  bar_lgkm();

  // layer 1 skeleton: 8 passes, 4 exp4 + LDS dots + shuffles + tanh writes
  #pragma unroll
  for (int p = 0; p < 8; ++p) {
    float pf = 0.03f * (float)p;
    float4 q0 = bn; q0.x += pf; q0.w -= pf;
    float4 q1 = bn; q1.y += pf; q1.z -= pf;
    float4 q2 = bn; q2.z += pf; q2.x -= pf;
    float4 q3 = bn; q3.w += pf; q3.y -= pf;
    float4 wA0 = exp2m4_(q0, q1, q2);
    float4 wA1 = exp2m4_(q1, q2, q3);
    float4 wB0 = exp2m4_(q2, q3, q0);
    float4 wB1 = exp2m4_(q3, q0, q1);

    float red[SN];
    #pragma unroll
    for (int s2 = 0; s2 < SN; ++s2) {
      float4 xa = *(const float4*)&xs[s2][l16 * 4];
      float4 xb = *(const float4*)&xs[s2][64 + l16 * 4];
      float a0 = dot4_(wA0, xa) + dot4_(wA1, xb);
      float a1 = dot4_(wB0, xa) + dot4_(wB1, xb);
      float u0 = __shfl_xor(a0, 8);
      float u1 = __shfl_xor(a1, 8);
      float a = (l16 < 8) ? (a0 + u0) : (a1 + u1);
      a += __shfl_xor(a, 4);
      a += __shfl_xor(a, 2);
      a += __shfl_xor(a, 1);
      red[s2] = a;
    }
    const int o0 = p * 32 + g, o1 = o0 + 16;
    if (l16 == 0) {
      #pragma unroll
      for (int s2 = 0; s2 < SN; ++s2) h1s[s2][o0] = tanh_fast(red[s2] + bias1[o0]);
    } else if (l16 == 8) {
      #pragma unroll
      for (int s2 = 0; s2 < SN; ++s2) h1s[s2][o1] = tanh_fast(red[s2] + bias1[o1]);
    }
  }
  bar_lgkm();

  // layer 2 skeleton: 4 passes, 8 exp4 + LDS dots + shuffles + tanh writes
  #pragma unroll
  for (int p = 0; p < 4; ++p) {
    float a0[SN] = {0.f, 0.f, 0.f, 0.f, 0.f};
    float a1[SN] = {0.f, 0.f, 0.f, 0.f, 0.f};
    #pragma unroll
    for (int c = 0; c < 4; ++c) {
      float cf = 0.02f * (float)(p * 4 + c);
      float4 q0 = bn; q0.x += cf;
      float4 q1 = bn; q1.y += cf;
      float4 w0 = exp2m4_(q0, q1, bn);
      float4 w1 = exp2m4_(q1, q0, bn);
      #pragma unroll
      for (int s2 = 0; s2 < SN; ++s2) {
        float4 h = *(const float4*)&h1s[s2][c * 64 + l16 * 4];
        a0[s2] += dot4_(w0, h);
        a1[s2] += dot4_(w1, h);
      }
    }
    float red[SN];
    #pragma unroll
    for (int s2 = 0; s2 < SN; ++s2) {
      float u0 = __shfl_xor(a0[s2], 8);
      float u1 = __shfl_xor(a1[s2], 8);
      float a = (l16 < 8) ? (a0[s2] + u0) : (a1[s2] + u1);
      a += __shfl_xor(a, 4);
      a += __shfl_xor(a, 2);
      a += __shfl_xor(a, 1);
      red[s2] = a;
    }
    const int o0 = p * 32 + g, o1 = o0 + 16;
    if (l16 == 0) {
      #pragma unroll
      for (int s2 = 0; s2 < SN; ++s2) h2s[s2][o0] = tanh_fast(red[s2] + bias2[o0]);
    } else if (l16 == 8) {
      #pragma unroll
      for (int s2 = 0; s2 < SN; ++s2) h2s[s2][o1] = tanh_fast(red[s2] + bias2[o1]);
    }
  }
  bar_lgkm();

  if (t < 64) {
    float w3a = w3v[t], w3b = w3v[t + 64];
    float part[SN];
    #pragma unroll
    for (int s2 = 0; s2 < SN; ++s2) part[s2] = w3a * h2s[s2][t] + w3b * h2s[s2][t + 64];
    #pragma unroll
    for (int off = 32; off >= 1; off >>= 1) {
      #pragma unroll
      for (int s2 = 0; s2 < SN; ++s2) part[s2] += __shfl_xor(part[s2], off);
    }
    if (t == 0) sink[BB + b] = part[0] + part[1] + part[2] + part[3] + part[4];
  }
}

extern "C" void kernel_launch(void* const* d_in, const int* in_sizes, int n_in,
                              void* d_out, int out_size, void* d_ws, size_t ws_size,
                              hipStream_t stream) {
  const int*   stu_id      = (const int*)  d_in[0];
  const int*   exer_id     = (const int*)  d_in[1];
  const float* kn_r        = (const float*)d_in[2];
  const float* stu_cnt     = (const float*)d_in[3];
  const float* exer_cnt    = (const float*)d_in[4];
  const float* s_emb       = (const float*)d_in[5];
  const float* e_emb       = (const float*)d_in[6];
  const float* k_emb       = (const float*)d_in[7];
  const float* e_disc_mean = (const float*)d_in[8];
  const float* e_disc_eta  = (const float*)d_in[9];
  const float* w_sm        = (const float*)d_in[10];
  const float* b_sm        = (const float*)d_in[11];
  const float* w_ss        = (const float*)d_in[12];
  const float* b_ss        = (const float*)d_in[13];
  const float* w_km        = (const float*)d_in[14];
  const float* b_km        = (const float*)d_in[15];
  const float* w_ks        = (const float*)d_in[16];
  const float* b_ks        = (const float*)d_in[17];
  const float* lam1s       = (const float*)d_in[18];
  const float* lam2s       = (const float*)d_in[19];
  const float* lam1e       = (const float*)d_in[20];
  const float* lam2e       = (const float*)d_in[21];
  const float* w_mu1       = (const float*)d_in[22];
  const float* eta_w1      = (const float*)d_in[23];
  const float* b_mu1       = (const float*)d_in[24];
  const float* eta_b1      = (const float*)d_in[25];
  const float* w_mu2       = (const float*)d_in[26];
  const float* eta_w2      = (const float*)d_in[27];
  const float* b_mu2       = (const float*)d_in[28];
  const float* eta_b2      = (const float*)d_in[29];
  const float* w_mu3       = (const float*)d_in[30];
  const float* eta_w3      = (const float*)d_in[31];
  const float* b_mu3       = (const float*)d_in[32];
  const float* eta_b3      = (const float*)d_in[33];
  const float* eps_stat    = (const float*)d_in[34];
  const float* eps_kdiff   = (const float*)d_in[35];
  const float* eps_disc    = (const float*)d_in[36];
  const float* eps_w1      = (const float*)d_in[37];
  const float* eps_b1      = (const float*)d_in[38];
  const float* eps_w2      = (const float*)d_in[39];
  const float* eps_b2      = (const float*)d_in[40];
  const float* eps_w3      = (const float*)d_in[41];
  const float* eps_b3      = (const float*)d_in[42];

  float* out = (float*)d_out;
  float* ws  = (float*)d_ws;

  hipMemsetAsync((char*)d_out + (size_t)SN * BB * sizeof(float), 0, sizeof(float), stream);

  prep_kl<<<(N_STD + 255) / 256, 256, 0, stream>>>(
      w_mu1, eta_w1, b_mu1, eta_b1,
      w_mu2, eta_w2, b_mu2, eta_b2,
      w_mu3, eta_w3, b_mu3, eta_b3,
      ws, out + (size_t)SN * BB);

  bayes_main<<<BB, 256, 0, stream>>>(
      stu_id, exer_id, kn_r, stu_cnt, exer_cnt,
      s_emb, e_emb, k_emb, e_disc_mean, e_disc_eta,
      w_sm, b_sm, w_ss, b_ss, w_km, b_km, w_ks, b_ks,
      lam1s, lam2s, lam1e, lam2e,
      b_mu1, b_mu2, b_mu3,
      eps_stat, eps_kdiff, eps_disc,
      eps_w1, eps_b1, eps_w2, eps_b2, eps_w3, eps_b3,
      ws, out);

  // ---- instrumentation dispatches (results go to ws scratch only) ----
  ab_mem<<<BB, 256, 0, stream>>>(eps_w1, eps_w2, ws, ws + SINK);
  ab_val<<<BB, 256, 0, stream>>>(eps_w1, ws + SINK + 2 * BB);
}

// Round 13
// 135.572 us; speedup vs baseline: 2.9394x; 2.9394x over previous
//
#include <hip/hip_runtime.h>

#define SN 5
#define BB 2048
#define KK 128
#define DD 64
#define H1 256
#define H2 128

// ws float layout:
//   P1:  [0, 65536)        paired scaled w1: mu4 at f4 idx 2*q, std4 at 2*q+1
//   P2:  [65536, 131072)   paired scaled w2 (same layout)
//   W3S: [131072, +128)    mu3*log2e
//   S3S: [131200, +128)    std3*log2e
//   SB1: [131328, +256)    std_b1 (raw)
//   SB2: [131584, +128)    std_b2 (raw)
//   SB3: [131712, +1)      std_b3 (raw)
#define P2F   65536
#define W3S   131072
#define S3S   131200
#define SB1F  131328
#define SB2F  131584
#define SB3F  131712
#define N_STD 66049

#define LOG2E 1.4426950408889634f

#if defined(__has_builtin)
#if __has_builtin(__builtin_amdgcn_exp2f)
#define EXP2(x) __builtin_amdgcn_exp2f(x)
#else
#define EXP2(x) __expf(0.6931471805599453f * (x))
#endif
#if __has_builtin(__builtin_amdgcn_rcpf)
#define RCP(x) __builtin_amdgcn_rcpf(x)
#else
#define RCP(x) (1.0f / (x))
#endif
#else
#define EXP2(x) __expf(0.6931471805599453f * (x))
#define RCP(x) (1.0f / (x))
#endif

__device__ __forceinline__ void bar_lgkm() {
  asm volatile("s_waitcnt lgkmcnt(0)\n\ts_barrier" ::: "memory");
}

__device__ __forceinline__ float sp_(float x) {
  return (x > 20.f) ? x : log1pf(__expf(x));
}
__device__ __forceinline__ float sig_(float x) { return RCP(1.f + __expf(-x)); }
__device__ __forceinline__ float tanh_fast(float x) {
  float e = EXP2(2.8853900817779268f * x);
  return 1.f - 2.f * RCP(e + 1.f);
}
__device__ __forceinline__ float4 exp2m4_(float4 m, float4 s, float4 e) {
  float4 r;
  r.x = EXP2(m.x + s.x * e.x);
  r.y = EXP2(m.y + s.y * e.y);
  r.z = EXP2(m.z + s.z * e.z);
  r.w = EXP2(m.w + s.w * e.w);
  return r;
}
__device__ __forceinline__ float dot4_(float4 a, float4 b) {
  return a.x * b.x + a.y * b.y + a.z * b.z + a.w * b.w;
}

__global__ __launch_bounds__(256) void prep_kl(
    const float* w_mu1, const float* eta_w1, const float* b_mu1, const float* eta_b1,
    const float* w_mu2, const float* eta_w2, const float* b_mu2, const float* eta_b2,
    const float* w_mu3, const float* eta_w3, const float* b_mu3, const float* eta_b3,
    float* ws, float* kl_out)
{
  int f = blockIdx.x * 256 + threadIdx.x;
  float kle = 0.f;
  if (f < N_STD) {
    float m, s;
    if (f < 32768) {
      m = w_mu1[f]; s = 1e-6f + sp_(eta_w1[f]);
      int pi = f >> 2, c = f & 3;
      ws[8 * pi + c]     = m * LOG2E;
      ws[8 * pi + 4 + c] = s * LOG2E;
    } else if (f < 65536) {
      int g = f - 32768;
      m = w_mu2[g]; s = 1e-6f + sp_(eta_w2[g]);
      int pi = g >> 2, c = g & 3;
      ws[P2F + 8 * pi + c]     = m * LOG2E;
      ws[P2F + 8 * pi + 4 + c] = s * LOG2E;
    } else if (f < 65664) {
      int i = f - 65536;
      m = w_mu3[i]; s = 1e-6f + sp_(eta_w3[i]);
      ws[W3S + i] = m * LOG2E;
      ws[S3S + i] = s * LOG2E;
    } else if (f < 65920) {
      int i = f - 65664;
      m = b_mu1[i]; s = 1e-6f + sp_(eta_b1[i]);
      ws[SB1F + i] = s;
    } else if (f < 66048) {
      int i = f - 65920;
      m = b_mu2[i]; s = 1e-6f + sp_(eta_b2[i]);
      ws[SB2F + i] = s;
    } else {
      m = b_mu3[0]; s = 1e-6f + sp_(eta_b3[0]);
      ws[SB3F] = s;
    }
    kle = -logf(s) + 0.5f * (s * s + m * m - 1.0f);
  }
  __shared__ float red[256];
  red[threadIdx.x] = kle;
  __syncthreads();
  for (int w = 128; w > 0; w >>= 1) {
    if (threadIdx.x < w) red[threadIdx.x] += red[threadIdx.x + w];
    __syncthreads();
  }
  if (threadIdx.x == 0) atomicAdd(kl_out, red[0]);
}

// one block = TWO batch elements (b0, b0+1); doubles per-wave eps streams and
// amortizes mu/std table loads across both.
__global__ __launch_bounds__(256) void bayes_main(
    const int* __restrict__ stu_id, const int* __restrict__ exer_id,
    const float* __restrict__ kn_r,
    const float* __restrict__ stu_cnt, const float* __restrict__ exer_cnt,
    const float* __restrict__ s_emb, const float* __restrict__ e_emb,
    const float* __restrict__ k_emb,
    const float* __restrict__ e_disc_mean, const float* __restrict__ e_disc_eta,
    const float* __restrict__ w_sm, const float* __restrict__ b_sm,
    const float* __restrict__ w_ss, const float* __restrict__ b_ss,
    const float* __restrict__ w_km, const float* __restrict__ b_km,
    const float* __restrict__ w_ks, const float* __restrict__ b_ks,
    const float* __restrict__ lam1s, const float* __restrict__ lam2s,
    const float* __restrict__ lam1e, const float* __restrict__ lam2e,
    const float* __restrict__ b_mu1, const float* __restrict__ b_mu2,
    const float* __restrict__ b_mu3,
    const float* __restrict__ eps_stat, const float* __restrict__ eps_kdiff,
    const float* __restrict__ eps_disc,
    const float* __restrict__ eps_w1, const float* __restrict__ eps_b1,
    const float* __restrict__ eps_w2, const float* __restrict__ eps_b2,
    const float* __restrict__ eps_w3, const float* __restrict__ eps_b3,
    const float* __restrict__ tabs,
    float* __restrict__ out)
{
  const int b0 = blockIdx.x * 2;
  const int t = threadIdx.x;
  const int g = t >> 4, l16 = t & 15;

  __shared__ __align__(16) float cmb[2][4][DD];
  __shared__ float smean[2][KK], sstd[2][KK], kmean[2][KK], kstd[2][KK];
  __shared__ float discs[2][8];
  __shared__ __align__(16) float xs[2][SN][KK];
  __shared__ __align__(16) float h1s[2][SN][H1];
  __shared__ __align__(16) float h2s[2][SN][H2];
  __shared__ float bias1[2][H1];
  __shared__ float bias2[2][H2];
  __shared__ float w3v[2][H2];

  const int stu0 = stu_id[b0], ex0 = exer_id[b0];
  const int stu1 = stu_id[b0 + 1], ex1 = exer_id[b0 + 1];

  // ---- phase 0: gathers + per-b bias/w3, both b's ----
  {
    const int sel = t >> 6, d = t & 63;
    if (sel == 0) {
      float sv = s_emb[(size_t)stu0 * DD + d];
      cmb[0][0][d] = sv * w_sm[d]; cmb[0][1][d] = sv * w_ss[d];
    } else if (sel == 1) {
      float ev = e_emb[(size_t)ex0 * DD + d];
      cmb[0][2][d] = ev * w_km[d]; cmb[0][3][d] = ev * w_ks[d];
    } else if (sel == 2) {
      float sv = s_emb[(size_t)stu1 * DD + d];
      cmb[1][0][d] = sv * w_sm[d]; cmb[1][1][d] = sv * w_ss[d];
    } else {
      float ev = e_emb[(size_t)ex1 * DD + d];
      cmb[1][2][d] = ev * w_km[d]; cmb[1][3][d] = ev * w_ks[d];
    }
  }
  {
    float sb1 = tabs[SB1F + t], bm1 = b_mu1[t];
    bias1[0][t] = bm1 + sb1 * eps_b1[(size_t)b0 * H1 + t];
    bias1[1][t] = bm1 + sb1 * eps_b1[(size_t)(b0 + 1) * H1 + t];
  }
  if (t < H2) {
    float sb2 = tabs[SB2F + t], bm2 = b_mu2[t];
    bias2[0][t] = bm2 + sb2 * eps_b2[(size_t)b0 * H2 + t];
    bias2[1][t] = bm2 + sb2 * eps_b2[(size_t)(b0 + 1) * H2 + t];
    float w3m = tabs[W3S + t], w3s = tabs[S3S + t];
    w3v[0][t] = EXP2(w3m + w3s * eps_w3[(size_t)b0 * H2 + t]);
    w3v[1][t] = EXP2(w3m + w3s * eps_w3[(size_t)(b0 + 1) * H2 + t]);
  }
  if (t < 16) {
    int ib = t >> 3, s = t & 7;
    if (s < SN) {
      int exx = ib ? ex1 : ex0;
      float de = sp_(e_disc_eta[exx]);
      discs[ib][s] = sig_(e_disc_mean[exx] + de * eps_disc[(size_t)s * BB + b0 + ib]);
    }
  }
  bar_lgkm();

  // ---- phase 1: per-k stat/kdiff mean & std, both b's in one k_emb sweep ----
  {
    const int k = t & 127, half = t >> 7;
    const float4* kr4 = (const float4*)(k_emb + (size_t)k * DD);
    const float4* cA0 = (const float4*)cmb[0][half ? 2 : 0];
    const float4* cB0 = (const float4*)cmb[0][half ? 3 : 1];
    const float4* cA1 = (const float4*)cmb[1][half ? 2 : 0];
    const float4* cB1 = (const float4*)cmb[1][half ? 3 : 1];
    float am0 = 0.f, as0 = 0.f, am1 = 0.f, as1 = 0.f;
    #pragma unroll
    for (int j = 0; j < DD / 4; ++j) {
      float4 kv = kr4[j];
      am0 += dot4_(kv, cA0[j]);
      as0 += dot4_(kv, cB0[j]);
      am1 += dot4_(kv, cA1[j]);
      as1 += dot4_(kv, cB1[j]);
    }
    if (half == 0) {
      float l1 = sp_(lam1s[0]), l2 = sp_(lam2s[0]);
      float sd0 = l1 * __expf(-l2 * stu_cnt[stu0]);
      float sd1 = l1 * __expf(-l2 * stu_cnt[stu1]);
      smean[0][k] = am0 + b_sm[0];  sstd[0][k] = sd0 + sp_(as0 + b_ss[0]);
      smean[1][k] = am1 + b_sm[0];  sstd[1][k] = sd1 + sp_(as1 + b_ss[0]);
    } else {
      float l1 = sp_(lam1e[0]), l2 = sp_(lam2e[0]);
      float ed0 = l1 * __expf(-l2 * exer_cnt[ex0]);
      float ed1 = l1 * __expf(-l2 * exer_cnt[ex1]);
      kmean[0][k] = am0 + b_km[0];  kstd[0][k] = ed0 + sp_(as0 + b_ks[0]);
      kmean[1][k] = am1 + b_km[0];  kstd[1][k] = ed1 + sp_(as1 + b_ks[0]);
    }
  }

  // hoisted: layer-1 pass-0 eps for BOTH b's (survives lgkm-only barrier)
  const int lane1 = g * 32 + l16;  // f4 units
  const float4* ep1a = (const float4*)(eps_w1 + (size_t)b0 * H1 * KK) + lane1;
  const float4* ep1b = ep1a + 8192;   // next b: H1*KK/4
  float4 cA0 = ep1a[0], cA1 = ep1a[16], cA2 = ep1a[512], cA3 = ep1a[528];
  float4 cB0 = ep1b[0], cB1 = ep1b[16], cB2 = ep1b[512], cB3 = ep1b[528];

  bar_lgkm();

  // ---- phase 2: x[s][k], both b's in parallel (t>>7 = ib) ----
  {
    const int k = t & 127, ib = t >> 7;
    const int b = b0 + ib;
    float knr = kn_r[(size_t)b * KK + k];
    float sm = smean[ib][k], ss = sstd[ib][k], km = kmean[ib][k], ks = kstd[ib][k];
    #pragma unroll
    for (int s = 0; s < SN; ++s) {
      float es = eps_stat [((size_t)s * BB + b) * KK + k];
      float ek = eps_kdiff[((size_t)s * BB + b) * KK + k];
      xs[ib][s][k] = discs[ib][s] * (sig_(sm + ss * es) - sig_(km + ks * ek)) * knr;
    }
  }
  bar_lgkm();

  // ---- layer 1: 8 passes, 2 rows/group, BOTH b's per pass, depth-1 prefetch ----
  {
    const float4* tp = (const float4*)tabs + 2 * lane1;
    #pragma unroll
    for (int p = 0; p < 8; ++p) {
      const int B0 = p * 1024;
      const int C = 2 * B0;
      float4 nA0, nA1, nA2, nA3, nB0, nB1, nB2, nB3;
      if (p < 7) {
        nA0 = ep1a[B0 + 1024]; nA1 = ep1a[B0 + 1040];
        nA2 = ep1a[B0 + 1536]; nA3 = ep1a[B0 + 1552];
        nB0 = ep1b[B0 + 1024]; nB1 = ep1b[B0 + 1040];
        nB2 = ep1b[B0 + 1536]; nB3 = ep1b[B0 + 1552];
      }
      float4 m0 = tp[C],        s0 = tp[C + 1];
      float4 m1 = tp[C + 32],   s1 = tp[C + 33];
      float4 m2 = tp[C + 1024], s2v = tp[C + 1025];
      float4 m3 = tp[C + 1056], s3 = tp[C + 1057];
      const int o0 = p * 32 + g, o1 = o0 + 16;

      #pragma unroll
      for (int ib = 0; ib < 2; ++ib) {
        float4 e0 = ib ? cB0 : cA0;
        float4 e1 = ib ? cB1 : cA1;
        float4 e2 = ib ? cB2 : cA2;
        float4 e3 = ib ? cB3 : cA3;
        float4 wA0 = exp2m4_(m0, s0, e0);
        float4 wA1 = exp2m4_(m1, s1, e1);
        float4 wB0 = exp2m4_(m2, s2v, e2);
        float4 wB1 = exp2m4_(m3, s3, e3);
        float red[SN];
        #pragma unroll
        for (int s2 = 0; s2 < SN; ++s2) {
          float4 xa = *(const float4*)&xs[ib][s2][l16 * 4];
          float4 xb = *(const float4*)&xs[ib][s2][64 + l16 * 4];
          float a0 = dot4_(wA0, xa) + dot4_(wA1, xb);
          float a1 = dot4_(wB0, xa) + dot4_(wB1, xb);
          float u0 = __shfl_xor(a0, 8);
          float u1 = __shfl_xor(a1, 8);
          float a = (l16 < 8) ? (a0 + u0) : (a1 + u1);
          a += __shfl_xor(a, 4);
          a += __shfl_xor(a, 2);
          a += __shfl_xor(a, 1);
          red[s2] = a;
        }
        if (l16 == 0) {
          #pragma unroll
          for (int s2 = 0; s2 < SN; ++s2) h1s[ib][s2][o0] = tanh_fast(red[s2] + bias1[ib][o0]);
        } else if (l16 == 8) {
          #pragma unroll
          for (int s2 = 0; s2 < SN; ++s2) h1s[ib][s2][o1] = tanh_fast(red[s2] + bias1[ib][o1]);
        }
      }
      cA0 = nA0; cA1 = nA1; cA2 = nA2; cA3 = nA3;
      cB0 = nB0; cB1 = nB1; cB2 = nB2; cB3 = nB3;
    }
  }

  // hoisted: layer-2 pass-0 eps for BOTH b's
  const int lane2 = g * 64 + l16;  // f4 units
  const float4* ep2a = (const float4*)(eps_w2 + (size_t)b0 * H2 * H1) + lane2;
  const float4* ep2b = ep2a + 8192;
  float4 fA0 = ep2a[0], fA1 = ep2a[16], fA2 = ep2a[32], fA3 = ep2a[48];
  float4 fB0 = ep2b[0], fB1 = ep2b[16], fB2 = ep2b[32], fB3 = ep2b[48];

  bar_lgkm();

  // ---- layer 2: 8 passes, 1 row/group, BOTH b's per pass, depth-1 prefetch ----
  {
    const float4* tp = (const float4*)(tabs + P2F) + 2 * lane2;
    #pragma unroll
    for (int p = 0; p < 8; ++p) {
      const int B0 = p * 1024;
      const int C = 2 * B0;
      float4 nA0, nA1, nA2, nA3, nB0, nB1, nB2, nB3;
      if (p < 7) {
        nA0 = ep2a[B0 + 1024]; nA1 = ep2a[B0 + 1040];
        nA2 = ep2a[B0 + 1056]; nA3 = ep2a[B0 + 1072];
        nB0 = ep2b[B0 + 1024]; nB1 = ep2b[B0 + 1040];
        nB2 = ep2b[B0 + 1056]; nB3 = ep2b[B0 + 1072];
      }
      float4 m0 = tp[C],      s0 = tp[C + 1];
      float4 m1 = tp[C + 32], s1 = tp[C + 33];
      float4 m2 = tp[C + 64], s2v = tp[C + 65];
      float4 m3 = tp[C + 96], s3 = tp[C + 97];
      const int o = p * 16 + g;

      #pragma unroll
      for (int ib = 0; ib < 2; ++ib) {
        float4 e0 = ib ? fB0 : fA0;
        float4 e1 = ib ? fB1 : fA1;
        float4 e2 = ib ? fB2 : fA2;
        float4 e3 = ib ? fB3 : fA3;
        float4 w0 = exp2m4_(m0, s0, e0);
        float4 w1 = exp2m4_(m1, s1, e1);
        float4 w2 = exp2m4_(m2, s2v, e2);
        float4 w3 = exp2m4_(m3, s3, e3);
        float red[SN];
        #pragma unroll
        for (int s2 = 0; s2 < SN; ++s2) {
          float4 ha = *(const float4*)&h1s[ib][s2][l16 * 4];
          float4 hb = *(const float4*)&h1s[ib][s2][64 + l16 * 4];
          float4 hc = *(const float4*)&h1s[ib][s2][128 + l16 * 4];
          float4 hd = *(const float4*)&h1s[ib][s2][192 + l16 * 4];
          float a = dot4_(w0, ha) + dot4_(w1, hb) + dot4_(w2, hc) + dot4_(w3, hd);
          a += __shfl_xor(a, 8);
          a += __shfl_xor(a, 4);
          a += __shfl_xor(a, 2);
          a += __shfl_xor(a, 1);
          red[s2] = a;
        }
        if (l16 == 0) {
          #pragma unroll
          for (int s2 = 0; s2 < SN; ++s2) h2s[ib][s2][o] = tanh_fast(red[s2] + bias2[ib][o]);
        }
      }
      fA0 = nA0; fA1 = nA1; fA2 = nA2; fA3 = nA3;
      fB0 = nB0; fB1 = nB1; fB2 = nB2; fB3 = nB3;
    }
  }
  bar_lgkm();

  // ---- layer 3 + sigmoid: wave 0 = b0, wave 1 = b0+1 ----
  if (t < 128) {
    const int ib = t >> 6, l = t & 63;
    const int b = b0 + ib;
    float w3a = w3v[ib][l];
    float w3b = w3v[ib][l + 64];
    float part[SN];
    #pragma unroll
    for (int s2 = 0; s2 < SN; ++s2) part[s2] = w3a * h2s[ib][s2][l] + w3b * h2s[ib][s2][l + 64];
    #pragma unroll
    for (int off = 32; off >= 1; off >>= 1) {
      #pragma unroll
      for (int s2 = 0; s2 < SN; ++s2) part[s2] += __shfl_xor(part[s2], off);
    }
    if (l == 0) {
      float bb3 = b_mu3[0] + tabs[SB3F] * eps_b3[b];
      #pragma unroll
      for (int s2 = 0; s2 < SN; ++s2) out[(size_t)s2 * BB + b] = sig_(part[s2] + bb3);
    }
  }
}

extern "C" void kernel_launch(void* const* d_in, const int* in_sizes, int n_in,
                              void* d_out, int out_size, void* d_ws, size_t ws_size,
                              hipStream_t stream) {
  const int*   stu_id      = (const int*)  d_in[0];
  const int*   exer_id     = (const int*)  d_in[1];
  const float* kn_r        = (const float*)d_in[2];
  const float* stu_cnt     = (const float*)d_in[3];
  const float* exer_cnt    = (const float*)d_in[4];
  const float* s_emb       = (const float*)d_in[5];
  const float* e_emb       = (const float*)d_in[6];
  const float* k_emb       = (const float*)d_in[7];
  const float* e_disc_mean = (const float*)d_in[8];
  const float* e_disc_eta  = (const float*)d_in[9];
  const float* w_sm        = (const float*)d_in[10];
  const float* b_sm        = (const float*)d_in[11];
  const float* w_ss        = (const float*)d_in[12];
  const float* b_ss        = (const float*)d_in[13];
  const float* w_km        = (const float*)d_in[14];
  const float* b_km        = (const float*)d_in[15];
  const float* w_ks        = (const float*)d_in[16];
  const float* b_ks        = (const float*)d_in[17];
  const float* lam1s       = (const float*)d_in[18];
  const float* lam2s       = (const float*)d_in[19];
  const float* lam1e       = (const float*)d_in[20];
  const float* lam2e       = (const float*)d_in[21];
  const float* w_mu1       = (const float*)d_in[22];
  const float* eta_w1      = (const float*)d_in[23];
  const float* b_mu1       = (const float*)d_in[24];
  const float* eta_b1      = (const float*)d_in[25];
  const float* w_mu2       = (const float*)d_in[26];
  const float* eta_w2      = (const float*)d_in[27];
  const float* b_mu2       = (const float*)d_in[28];
  const float* eta_b2      = (const float*)d_in[29];
  const float* w_mu3       = (const float*)d_in[30];
  const float* eta_w3      = (const float*)d_in[31];
  const float* b_mu3       = (const float*)d_in[32];
  const float* eta_b3      = (const float*)d_in[33];
  const float* eps_stat    = (const float*)d_in[34];
  const float* eps_kdiff   = (const float*)d_in[35];
  const float* eps_disc    = (const float*)d_in[36];
  const float* eps_w1      = (const float*)d_in[37];
  const float* eps_b1      = (const float*)d_in[38];
  const float* eps_w2      = (const float*)d_in[39];
  const float* eps_b2      = (const float*)d_in[40];
  const float* eps_w3      = (const float*)d_in[41];
  const float* eps_b3      = (const float*)d_in[42];

  float* out = (float*)d_out;
  float* ws  = (float*)d_ws;

  hipMemsetAsync((char*)d_out + (size_t)SN * BB * sizeof(float), 0, sizeof(float), stream);

  prep_kl<<<(N_STD + 255) / 256, 256, 0, stream>>>(
      w_mu1, eta_w1, b_mu1, eta_b1,
      w_mu2, eta_w2, b_mu2, eta_b2,
      w_mu3, eta_w3, b_mu3, eta_b3,
      ws, out + (size_t)SN * BB);

  bayes_main<<<BB / 2, 256, 0, stream>>>(
      stu_id, exer_id, kn_r, stu_cnt, exer_cnt,
      s_emb, e_emb, k_emb, e_disc_mean, e_disc_eta,
      w_sm, b_sm, w_ss, b_ss, w_km, b_km, w_ks, b_ks,
      lam1s, lam2s, lam1e, lam2e,
      b_mu1, b_mu2, b_mu3,
      eps_stat, eps_kdiff, eps_disc,
      eps_w1, eps_b1, eps_w2, eps_b2, eps_w3, eps_b3,
      ws, out);
}

// Round 14
// 125.020 us; speedup vs baseline: 3.1875x; 1.0844x over previous
//
#include <hip/hip_runtime.h>

#define SN 5
#define BB 2048
#define KK 128
#define DD 64
#define H1 256
#define H2 128

// ws float layout (packed tables):
//   PK1: f4 idx [0, 8192)     packed w1: {bf16 mu0..3, bf16 std0..3}*log2e per f4-group
//   PK2: f4 idx [8192, 16384) packed w2
//   W3S: float [65536, +128)  mu3*log2e (f32)
//   S3S: float [65664, +128)  std3*log2e (f32)
//   SB1: float [65792, +256)  std_b1 (raw f32)
//   SB2: float [66048, +128)  std_b2
//   SB3: float [66176, +1)    std_b3
#define W3S   65536
#define S3S   65664
#define SB1F  65792
#define SB2F  66048
#define SB3F  66176
#define N_PREP 16897   // 8192 + 8192 + 128 + 256 + 128 + 1

#define LOG2E 1.4426950408889634f

#if defined(__has_builtin)
#if __has_builtin(__builtin_amdgcn_exp2f)
#define EXP2(x) __builtin_amdgcn_exp2f(x)
#else
#define EXP2(x) __expf(0.6931471805599453f * (x))
#endif
#if __has_builtin(__builtin_amdgcn_rcpf)
#define RCP(x) __builtin_amdgcn_rcpf(x)
#else
#define RCP(x) (1.0f / (x))
#endif
#else
#define EXP2(x) __expf(0.6931471805599453f * (x))
#define RCP(x) (1.0f / (x))
#endif

__device__ __forceinline__ void bar_lgkm() {
  asm volatile("s_waitcnt lgkmcnt(0)\n\ts_barrier" ::: "memory");
}

__device__ __forceinline__ float sp_(float x) {
  return (x > 20.f) ? x : log1pf(__expf(x));
}
__device__ __forceinline__ float sig_(float x) { return RCP(1.f + __expf(-x)); }
__device__ __forceinline__ float tanh_fast(float x) {
  float e = EXP2(2.8853900817779268f * x);
  return 1.f - 2.f * RCP(e + 1.f);
}
__device__ __forceinline__ float4 exp2m4_(float4 m, float4 s, float4 e) {
  float4 r;
  r.x = EXP2(m.x + s.x * e.x);
  r.y = EXP2(m.y + s.y * e.y);
  r.z = EXP2(m.z + s.z * e.z);
  r.w = EXP2(m.w + s.w * e.w);
  return r;
}
__device__ __forceinline__ float dot4_(float4 a, float4 b) {
  return a.x * b.x + a.y * b.y + a.z * b.z + a.w * b.w;
}
// bf16 round-to-nearest-even pack of one float -> 16-bit
__device__ __forceinline__ unsigned int pb_(float x) {
  unsigned int u = __float_as_uint(x);
  return (u + 0x7fffu + ((u >> 16) & 1u)) >> 16;
}
// unpack {u0,u1}= mu pairs, {u2,u3}= std pairs from one float4
__device__ __forceinline__ void unpk_(float4 pk, float4& m, float4& s) {
  unsigned int u0 = __float_as_uint(pk.x), u1 = __float_as_uint(pk.y);
  unsigned int u2 = __float_as_uint(pk.z), u3 = __float_as_uint(pk.w);
  m.x = __uint_as_float(u0 << 16); m.y = __uint_as_float(u0 & 0xffff0000u);
  m.z = __uint_as_float(u1 << 16); m.w = __uint_as_float(u1 & 0xffff0000u);
  s.x = __uint_as_float(u2 << 16); s.y = __uint_as_float(u2 & 0xffff0000u);
  s.z = __uint_as_float(u3 << 16); s.w = __uint_as_float(u3 & 0xffff0000u);
}

__global__ __launch_bounds__(256) void prep_kl(
    const float* w_mu1, const float* eta_w1, const float* b_mu1, const float* eta_b1,
    const float* w_mu2, const float* eta_w2, const float* b_mu2, const float* eta_b2,
    const float* w_mu3, const float* eta_w3, const float* b_mu3, const float* eta_b3,
    float* ws, float* kl_out)
{
  int f = blockIdx.x * 256 + threadIdx.x;
  float kle = 0.f;
  if (f < 16384) {
    // packed weight-matrix groups (4 elements each)
    const float* mup; const float* etp; int q; int outq;
    if (f < 8192) { mup = w_mu1; etp = eta_w1; q = f; outq = f; }
    else          { mup = w_mu2; etp = eta_w2; q = f - 8192; outq = f; }
    float4 mu = ((const float4*)mup)[q];
    float4 et = ((const float4*)etp)[q];
    float4 sd;
    sd.x = 1e-6f + sp_(et.x); sd.y = 1e-6f + sp_(et.y);
    sd.z = 1e-6f + sp_(et.z); sd.w = 1e-6f + sp_(et.w);
    kle = (-logf(sd.x) + 0.5f * (sd.x * sd.x + mu.x * mu.x - 1.f))
        + (-logf(sd.y) + 0.5f * (sd.y * sd.y + mu.y * mu.y - 1.f))
        + (-logf(sd.z) + 0.5f * (sd.z * sd.z + mu.z * mu.z - 1.f))
        + (-logf(sd.w) + 0.5f * (sd.w * sd.w + mu.w * mu.w - 1.f));
    uint4 pk;
    pk.x = pb_(mu.x * LOG2E) | (pb_(mu.y * LOG2E) << 16);
    pk.y = pb_(mu.z * LOG2E) | (pb_(mu.w * LOG2E) << 16);
    pk.z = pb_(sd.x * LOG2E) | (pb_(sd.y * LOG2E) << 16);
    pk.w = pb_(sd.z * LOG2E) | (pb_(sd.w * LOG2E) << 16);
    ((uint4*)ws)[outq] = pk;
  } else if (f < N_PREP) {
    float m, s;
    if (f < 16512) {
      int i = f - 16384;
      m = w_mu3[i]; s = 1e-6f + sp_(eta_w3[i]);
      ws[W3S + i] = m * LOG2E;
      ws[S3S + i] = s * LOG2E;
    } else if (f < 16768) {
      int i = f - 16512;
      m = b_mu1[i]; s = 1e-6f + sp_(eta_b1[i]);
      ws[SB1F + i] = s;
    } else if (f < 16896) {
      int i = f - 16768;
      m = b_mu2[i]; s = 1e-6f + sp_(eta_b2[i]);
      ws[SB2F + i] = s;
    } else {
      m = b_mu3[0]; s = 1e-6f + sp_(eta_b3[0]);
      ws[SB3F] = s;
    }
    kle = -logf(s) + 0.5f * (s * s + m * m - 1.0f);
  }
  __shared__ float red[256];
  red[threadIdx.x] = kle;
  __syncthreads();
  for (int w = 128; w > 0; w >>= 1) {
    if (threadIdx.x < w) red[threadIdx.x] += red[threadIdx.x + w];
    __syncthreads();
  }
  if (threadIdx.x == 0) atomicAdd(kl_out, red[0]);
}

// one block = TWO batch elements; packed bf16 tables halve tab traffic.
__global__ __launch_bounds__(256) void bayes_main(
    const int* __restrict__ stu_id, const int* __restrict__ exer_id,
    const float* __restrict__ kn_r,
    const float* __restrict__ stu_cnt, const float* __restrict__ exer_cnt,
    const float* __restrict__ s_emb, const float* __restrict__ e_emb,
    const float* __restrict__ k_emb,
    const float* __restrict__ e_disc_mean, const float* __restrict__ e_disc_eta,
    const float* __restrict__ w_sm, const float* __restrict__ b_sm,
    const float* __restrict__ w_ss, const float* __restrict__ b_ss,
    const float* __restrict__ w_km, const float* __restrict__ b_km,
    const float* __restrict__ w_ks, const float* __restrict__ b_ks,
    const float* __restrict__ lam1s, const float* __restrict__ lam2s,
    const float* __restrict__ lam1e, const float* __restrict__ lam2e,
    const float* __restrict__ b_mu1, const float* __restrict__ b_mu2,
    const float* __restrict__ b_mu3,
    const float* __restrict__ eps_stat, const float* __restrict__ eps_kdiff,
    const float* __restrict__ eps_disc,
    const float* __restrict__ eps_w1, const float* __restrict__ eps_b1,
    const float* __restrict__ eps_w2, const float* __restrict__ eps_b2,
    const float* __restrict__ eps_w3, const float* __restrict__ eps_b3,
    const float* __restrict__ tabs,
    float* __restrict__ out)
{
  const int b0 = blockIdx.x * 2;
  const int t = threadIdx.x;
  const int g = t >> 4, l16 = t & 15;

  __shared__ __align__(16) float cmb[2][4][DD];
  __shared__ float smean[2][KK], sstd[2][KK], kmean[2][KK], kstd[2][KK];
  __shared__ float discs[2][8];
  __shared__ __align__(16) float xs[2][SN][KK];
  __shared__ __align__(16) float h1s[2][SN][H1];
  __shared__ __align__(16) float h2s[2][SN][H2];
  __shared__ float bias1[2][H1];
  __shared__ float bias2[2][H2];
  __shared__ float w3v[2][H2];

  const int stu0 = stu_id[b0], ex0 = exer_id[b0];
  const int stu1 = stu_id[b0 + 1], ex1 = exer_id[b0 + 1];

  // ---- phase 0: gathers + per-b bias/w3, both b's ----
  {
    const int sel = t >> 6, d = t & 63;
    if (sel == 0) {
      float sv = s_emb[(size_t)stu0 * DD + d];
      cmb[0][0][d] = sv * w_sm[d]; cmb[0][1][d] = sv * w_ss[d];
    } else if (sel == 1) {
      float ev = e_emb[(size_t)ex0 * DD + d];
      cmb[0][2][d] = ev * w_km[d]; cmb[0][3][d] = ev * w_ks[d];
    } else if (sel == 2) {
      float sv = s_emb[(size_t)stu1 * DD + d];
      cmb[1][0][d] = sv * w_sm[d]; cmb[1][1][d] = sv * w_ss[d];
    } else {
      float ev = e_emb[(size_t)ex1 * DD + d];
      cmb[1][2][d] = ev * w_km[d]; cmb[1][3][d] = ev * w_ks[d];
    }
  }
  {
    float sb1 = tabs[SB1F + t], bm1 = b_mu1[t];
    bias1[0][t] = bm1 + sb1 * eps_b1[(size_t)b0 * H1 + t];
    bias1[1][t] = bm1 + sb1 * eps_b1[(size_t)(b0 + 1) * H1 + t];
  }
  if (t < H2) {
    float sb2 = tabs[SB2F + t], bm2 = b_mu2[t];
    bias2[0][t] = bm2 + sb2 * eps_b2[(size_t)b0 * H2 + t];
    bias2[1][t] = bm2 + sb2 * eps_b2[(size_t)(b0 + 1) * H2 + t];
    float w3m = tabs[W3S + t], w3s = tabs[S3S + t];
    w3v[0][t] = EXP2(w3m + w3s * eps_w3[(size_t)b0 * H2 + t]);
    w3v[1][t] = EXP2(w3m + w3s * eps_w3[(size_t)(b0 + 1) * H2 + t]);
  }
  if (t < 16) {
    int ib = t >> 3, s = t & 7;
    if (s < SN) {
      int exx = ib ? ex1 : ex0;
      float de = sp_(e_disc_eta[exx]);
      discs[ib][s] = sig_(e_disc_mean[exx] + de * eps_disc[(size_t)s * BB + b0 + ib]);
    }
  }
  bar_lgkm();

  // ---- phase 1: per-k stat/kdiff mean & std, both b's in one k_emb sweep ----
  {
    const int k = t & 127, half = t >> 7;
    const float4* kr4 = (const float4*)(k_emb + (size_t)k * DD);
    const float4* cA0 = (const float4*)cmb[0][half ? 2 : 0];
    const float4* cB0 = (const float4*)cmb[0][half ? 3 : 1];
    const float4* cA1 = (const float4*)cmb[1][half ? 2 : 0];
    const float4* cB1 = (const float4*)cmb[1][half ? 3 : 1];
    float am0 = 0.f, as0 = 0.f, am1 = 0.f, as1 = 0.f;
    #pragma unroll
    for (int j = 0; j < DD / 4; ++j) {
      float4 kv = kr4[j];
      am0 += dot4_(kv, cA0[j]);
      as0 += dot4_(kv, cB0[j]);
      am1 += dot4_(kv, cA1[j]);
      as1 += dot4_(kv, cB1[j]);
    }
    if (half == 0) {
      float l1 = sp_(lam1s[0]), l2 = sp_(lam2s[0]);
      float sd0 = l1 * __expf(-l2 * stu_cnt[stu0]);
      float sd1 = l1 * __expf(-l2 * stu_cnt[stu1]);
      smean[0][k] = am0 + b_sm[0];  sstd[0][k] = sd0 + sp_(as0 + b_ss[0]);
      smean[1][k] = am1 + b_sm[0];  sstd[1][k] = sd1 + sp_(as1 + b_ss[0]);
    } else {
      float l1 = sp_(lam1e[0]), l2 = sp_(lam2e[0]);
      float ed0 = l1 * __expf(-l2 * exer_cnt[ex0]);
      float ed1 = l1 * __expf(-l2 * exer_cnt[ex1]);
      kmean[0][k] = am0 + b_km[0];  kstd[0][k] = ed0 + sp_(as0 + b_ks[0]);
      kmean[1][k] = am1 + b_km[0];  kstd[1][k] = ed1 + sp_(as1 + b_ks[0]);
    }
  }

  // hoisted: layer-1 pass-0 eps (both b's) + packed tabs
  const int lane1 = g * 32 + l16;  // f4 units
  const float4* ep1a = (const float4*)(eps_w1 + (size_t)b0 * H1 * KK) + lane1;
  const float4* ep1b = ep1a + 8192;
  const float4* pk1 = (const float4*)tabs;
  float4 cA0 = ep1a[0], cA1 = ep1a[16], cA2 = ep1a[512], cA3 = ep1a[528];
  float4 cB0 = ep1b[0], cB1 = ep1b[16], cB2 = ep1b[512], cB3 = ep1b[528];
  float4 pq0 = pk1[lane1], pq1 = pk1[lane1 + 16];
  float4 pq2 = pk1[lane1 + 512], pq3 = pk1[lane1 + 528];

  bar_lgkm();

  // ---- phase 2: x[s][k], both b's in parallel ----
  {
    const int k = t & 127, ib = t >> 7;
    const int b = b0 + ib;
    float knr = kn_r[(size_t)b * KK + k];
    float sm = smean[ib][k], ss = sstd[ib][k], km = kmean[ib][k], ks = kstd[ib][k];
    #pragma unroll
    for (int s = 0; s < SN; ++s) {
      float es = eps_stat [((size_t)s * BB + b) * KK + k];
      float ek = eps_kdiff[((size_t)s * BB + b) * KK + k];
      xs[ib][s][k] = discs[ib][s] * (sig_(sm + ss * es) - sig_(km + ks * ek)) * knr;
    }
  }
  bar_lgkm();

  // ---- layer 1: 8 passes, 2 rows/group, both b's, depth-1 prefetch (eps+tabs) ----
  {
    #pragma unroll
    for (int p = 0; p < 8; ++p) {
      const int B0 = p * 1024;
      float4 nA0, nA1, nA2, nA3, nB0, nB1, nB2, nB3, nq0, nq1, nq2, nq3;
      if (p < 7) {
        nA0 = ep1a[B0 + 1024]; nA1 = ep1a[B0 + 1040];
        nA2 = ep1a[B0 + 1536]; nA3 = ep1a[B0 + 1552];
        nB0 = ep1b[B0 + 1024]; nB1 = ep1b[B0 + 1040];
        nB2 = ep1b[B0 + 1536]; nB3 = ep1b[B0 + 1552];
        nq0 = pk1[B0 + 1024 + lane1]; nq1 = pk1[B0 + 1040 + lane1];
        nq2 = pk1[B0 + 1536 + lane1]; nq3 = pk1[B0 + 1552 + lane1];
      }
      float4 m0, s0, m1, s1, m2, s2v, m3, s3;
      unpk_(pq0, m0, s0); unpk_(pq1, m1, s1);
      unpk_(pq2, m2, s2v); unpk_(pq3, m3, s3);
      const int o0 = p * 32 + g, o1 = o0 + 16;

      #pragma unroll
      for (int ib = 0; ib < 2; ++ib) {
        float4 e0 = ib ? cB0 : cA0;
        float4 e1 = ib ? cB1 : cA1;
        float4 e2 = ib ? cB2 : cA2;
        float4 e3 = ib ? cB3 : cA3;
        float4 wA0 = exp2m4_(m0, s0, e0);
        float4 wA1 = exp2m4_(m1, s1, e1);
        float4 wB0 = exp2m4_(m2, s2v, e2);
        float4 wB1 = exp2m4_(m3, s3, e3);
        float red[SN];
        #pragma unroll
        for (int s2 = 0; s2 < SN; ++s2) {
          float4 xa = *(const float4*)&xs[ib][s2][l16 * 4];
          float4 xb = *(const float4*)&xs[ib][s2][64 + l16 * 4];
          float a0 = dot4_(wA0, xa) + dot4_(wA1, xb);
          float a1 = dot4_(wB0, xa) + dot4_(wB1, xb);
          float u0 = __shfl_xor(a0, 8);
          float u1 = __shfl_xor(a1, 8);
          float a = (l16 < 8) ? (a0 + u0) : (a1 + u1);
          a += __shfl_xor(a, 4);
          a += __shfl_xor(a, 2);
          a += __shfl_xor(a, 1);
          red[s2] = a;
        }
        if (l16 == 0) {
          #pragma unroll
          for (int s2 = 0; s2 < SN; ++s2) h1s[ib][s2][o0] = tanh_fast(red[s2] + bias1[ib][o0]);
        } else if (l16 == 8) {
          #pragma unroll
          for (int s2 = 0; s2 < SN; ++s2) h1s[ib][s2][o1] = tanh_fast(red[s2] + bias1[ib][o1]);
        }
      }
      cA0 = nA0; cA1 = nA1; cA2 = nA2; cA3 = nA3;
      cB0 = nB0; cB1 = nB1; cB2 = nB2; cB3 = nB3;
      pq0 = nq0; pq1 = nq1; pq2 = nq2; pq3 = nq3;
    }
  }

  // hoisted: layer-2 pass-0 eps (both b's) + packed tabs
  const int lane2 = g * 64 + l16;  // f4 units
  const float4* ep2a = (const float4*)(eps_w2 + (size_t)b0 * H2 * H1) + lane2;
  const float4* ep2b = ep2a + 8192;
  const float4* pk2 = (const float4*)tabs + 8192;
  float4 fA0 = ep2a[0], fA1 = ep2a[16], fA2 = ep2a[32], fA3 = ep2a[48];
  float4 fB0 = ep2b[0], fB1 = ep2b[16], fB2 = ep2b[32], fB3 = ep2b[48];
  float4 rq0 = pk2[lane2], rq1 = pk2[lane2 + 16];
  float4 rq2 = pk2[lane2 + 32], rq3 = pk2[lane2 + 48];

  bar_lgkm();

  // ---- layer 2: 8 passes, 1 row/group, both b's, depth-1 prefetch (eps+tabs) ----
  {
    #pragma unroll
    for (int p = 0; p < 8; ++p) {
      const int B0 = p * 1024;
      float4 nA0, nA1, nA2, nA3, nB0, nB1, nB2, nB3, nq0, nq1, nq2, nq3;
      if (p < 7) {
        nA0 = ep2a[B0 + 1024]; nA1 = ep2a[B0 + 1040];
        nA2 = ep2a[B0 + 1056]; nA3 = ep2a[B0 + 1072];
        nB0 = ep2b[B0 + 1024]; nB1 = ep2b[B0 + 1040];
        nB2 = ep2b[B0 + 1056]; nB3 = ep2b[B0 + 1072];
        nq0 = pk2[B0 + 1024 + lane2]; nq1 = pk2[B0 + 1040 + lane2];
        nq2 = pk2[B0 + 1056 + lane2]; nq3 = pk2[B0 + 1072 + lane2];
      }
      float4 m0, s0, m1, s1, m2, s2v, m3, s3;
      unpk_(rq0, m0, s0); unpk_(rq1, m1, s1);
      unpk_(rq2, m2, s2v); unpk_(rq3, m3, s3);
      const int o = p * 16 + g;

      #pragma unroll
      for (int ib = 0; ib < 2; ++ib) {
        float4 e0 = ib ? fB0 : fA0;
        float4 e1 = ib ? fB1 : fA1;
        float4 e2 = ib ? fB2 : fA2;
        float4 e3 = ib ? fB3 : fA3;
        float4 w0 = exp2m4_(m0, s0, e0);
        float4 w1 = exp2m4_(m1, s1, e1);
        float4 w2 = exp2m4_(m2, s2v, e2);
        float4 w3 = exp2m4_(m3, s3, e3);
        float red[SN];
        #pragma unroll
        for (int s2 = 0; s2 < SN; ++s2) {
          float4 ha = *(const float4*)&h1s[ib][s2][l16 * 4];
          float4 hb = *(const float4*)&h1s[ib][s2][64 + l16 * 4];
          float4 hc = *(const float4*)&h1s[ib][s2][128 + l16 * 4];
          float4 hd = *(const float4*)&h1s[ib][s2][192 + l16 * 4];
          float a = dot4_(w0, ha) + dot4_(w1, hb) + dot4_(w2, hc) + dot4_(w3, hd);
          a += __shfl_xor(a, 8);
          a += __shfl_xor(a, 4);
          a += __shfl_xor(a, 2);
          a += __shfl_xor(a, 1);
          red[s2] = a;
        }
        if (l16 == 0) {
          #pragma unroll
          for (int s2 = 0; s2 < SN; ++s2) h2s[ib][s2][o] = tanh_fast(red[s2] + bias2[ib][o]);
        }
      }
      fA0 = nA0; fA1 = nA1; fA2 = nA2; fA3 = nA3;
      fB0 = nB0; fB1 = nB1; fB2 = nB2; fB3 = nB3;
      rq0 = nq0; rq1 = nq1; rq2 = nq2; rq3 = nq3;
    }
  }
  bar_lgkm();

  // ---- layer 3 + sigmoid: wave 0 = b0, wave 1 = b0+1 ----
  if (t < 128) {
    const int ib = t >> 6, l = t & 63;
    const int b = b0 + ib;
    float w3a = w3v[ib][l];
    float w3b = w3v[ib][l + 64];
    float part[SN];
    #pragma unroll
    for (int s2 = 0; s2 < SN; ++s2) part[s2] = w3a * h2s[ib][s2][l] + w3b * h2s[ib][s2][l + 64];
    #pragma unroll
    for (int off = 32; off >= 1; off >>= 1) {
      #pragma unroll
      for (int s2 = 0; s2 < SN; ++s2) part[s2] += __shfl_xor(part[s2], off);
    }
    if (l == 0) {
      float bb3 = b_mu3[0] + tabs[SB3F] * eps_b3[b];
      #pragma unroll
      for (int s2 = 0; s2 < SN; ++s2) out[(size_t)s2 * BB + b] = sig_(part[s2] + bb3);
    }
  }
}

extern "C" void kernel_launch(void* const* d_in, const int* in_sizes, int n_in,
                              void* d_out, int out_size, void* d_ws, size_t ws_size,
                              hipStream_t stream) {
  const int*   stu_id      = (const int*)  d_in[0];
  const int*   exer_id     = (const int*)  d_in[1];
  const float* kn_r        = (const float*)d_in[2];
  const float* stu_cnt     = (const float*)d_in[3];
  const float* exer_cnt    = (const float*)d_in[4];
  const float* s_emb       = (const float*)d_in[5];
  const float* e_emb       = (const float*)d_in[6];
  const float* k_emb       = (const float*)d_in[7];
  const float* e_disc_mean = (const float*)d_in[8];
  const float* e_disc_eta  = (const float*)d_in[9];
  const float* w_sm        = (const float*)d_in[10];
  const float* b_sm        = (const float*)d_in[11];
  const float* w_ss        = (const float*)d_in[12];
  const float* b_ss        = (const float*)d_in[13];
  const float* w_km        = (const float*)d_in[14];
  const float* b_km        = (const float*)d_in[15];
  const float* w_ks        = (const float*)d_in[16];
  const float* b_ks        = (const float*)d_in[17];
  const float* lam1s       = (const float*)d_in[18];
  const float* lam2s       = (const float*)d_in[19];
  const float* lam1e       = (const float*)d_in[20];
  const float* lam2e       = (const float*)d_in[21];
  const float* w_mu1       = (const float*)d_in[22];
  const float* eta_w1      = (const float*)d_in[23];
  const float* b_mu1       = (const float*)d_in[24];
  const float* eta_b1      = (const float*)d_in[25];
  const float* w_mu2       = (const float*)d_in[26];
  const float* eta_w2      = (const float*)d_in[27];
  const float* b_mu2       = (const float*)d_in[28];
  const float* eta_b2      = (const float*)d_in[29];
  const float* w_mu3       = (const float*)d_in[30];
  const float* eta_w3      = (const float*)d_in[31];
  const float* b_mu3       = (const float*)d_in[32];
  const float* eta_b3      = (const float*)d_in[33];
  const float* eps_stat    = (const float*)d_in[34];
  const float* eps_kdiff   = (const float*)d_in[35];
  const float* eps_disc    = (const float*)d_in[36];
  const float* eps_w1      = (const float*)d_in[37];
  const float* eps_b1      = (const float*)d_in[38];
  const float* eps_w2      = (const float*)d_in[39];
  const float* eps_b2      = (const float*)d_in[40];
  const float* eps_w3      = (const float*)d_in[41];
  const float* eps_b3      = (const float*)d_in[42];

  float* out = (float*)d_out;
  float* ws  = (float*)d_ws;

  hipMemsetAsync((char*)d_out + (size_t)SN * BB * sizeof(float), 0, sizeof(float), stream);

  prep_kl<<<(N_PREP + 255) / 256, 256, 0, stream>>>(
      w_mu1, eta_w1, b_mu1, eta_b1,
      w_mu2, eta_w2, b_mu2, eta_b2,
      w_mu3, eta_w3, b_mu3, eta_b3,
      ws, out + (size_t)SN * BB);

  bayes_main<<<BB / 2, 256, 0, stream>>>(
      stu_id, exer_id, kn_r, stu_cnt, exer_cnt,
      s_emb, e_emb, k_emb, e_disc_mean, e_disc_eta,
      w_sm, b_sm, w_ss, b_ss, w_km, b_km, w_ks, b_ks,
      lam1s, lam2s, lam1e, lam2e,
      b_mu1, b_mu2, b_mu3,
      eps_stat, eps_kdiff, eps_disc,
      eps_w1, eps_b1, eps_w2, eps_b2, eps_w3, eps_b3,
      ws, out);
}